// Round 1
// baseline (667.941 us; speedup 1.0000x reference)
//
#include <hip/hip_runtime.h>
#include <stdint.h>

// IrrepsLinear: out[n,m,:] = x[n,m,:] @ W[seg(m)]
// N=50000 nodes, M=16 spherical components, C_in=C_out=128, 4 weight matrices.
// Strategy: bf16 MFMA (threshold permits), weights register-resident per wave,
// pure HBM streaming of x/out. Floor ~130us at 6.3 TB/s for 819 MB.

typedef __attribute__((ext_vector_type(8))) short short8;   // 8 bf16 in 4 VGPRs
typedef __attribute__((ext_vector_type(4))) float floatx4;

static __device__ __forceinline__ unsigned short f2bf(float f) {
    // round-to-nearest-even fp32 -> bf16
    uint32_t u = __builtin_bit_cast(uint32_t, f);
    uint32_t r = (u + 0x7FFFu + ((u >> 16) & 1u)) >> 16;
    return (unsigned short)r;
}

// Pack weights (4 x 128 x 128 fp32, row-major [s][c][d]) into bf16 in exact
// MFMA B-fragment order for mfma_f32_16x16x32_bf16:
//   B[k][ncol]: lane holds col = lane&15, k = (lane>>4)*8 + j, j=0..7
// Layout: wp[(((s*8 + dt)*4 + kt)*64 + lane)*8 + j]
//   c = kt*32 + (lane>>4)*8 + j ; d = dt*16 + (lane&15)
__global__ void pack_weights_kernel(const float* __restrict__ w,
                                    unsigned short* __restrict__ wp) {
    int tid = blockIdx.x * 256 + threadIdx.x;      // 0..65535
    int j    = tid & 7;
    int lane = (tid >> 3) & 63;
    int kt   = (tid >> 9) & 3;
    int dt   = (tid >> 11) & 7;
    int s    = (tid >> 14) & 3;
    int c = kt * 32 + (lane >> 4) * 8 + j;
    int d = dt * 16 + (lane & 15);
    wp[tid] = f2bf(w[((size_t)s * 128 + c) * 128 + d]);
}

// Main kernel: 512 blocks x 256 threads = 2048 waves.
// wave -> (m = waveId>>7, stripe of 16-node tiles, stride 128 waves/m).
// 50000 nodes = 3125 tiles of 16, exactly.
__global__ __launch_bounds__(256, 2) void irreps_main_kernel(
    const float* __restrict__ x, const unsigned short* __restrict__ wp,
    const int* __restrict__ seg_ids, float* __restrict__ out)
{
    const int lane   = threadIdx.x & 63;
    const int waveId = blockIdx.x * 4 + (threadIdx.x >> 6);  // 0..2047
    const int m      = waveId >> 7;                          // 0..15
    const int w_in_m = waveId & 127;
    const int seg    = seg_ids[m];                           // wave-uniform
    const int q      = lane >> 4;                            // 0..3
    const int ln15   = lane & 15;

    // B fragments for this wave's weight matrix: 8 d-tiles x 4 k-tiles.
    // 32 x 16B = 128 VGPRs, register-resident for the whole kernel.
    short8 B[8][4];
    {
        const unsigned short* wb = wp + ((size_t)seg << 14);  // seg*8*4*64*8
        #pragma unroll
        for (int dt = 0; dt < 8; ++dt)
            #pragma unroll
            for (int kt = 0; kt < 4; ++kt)
                B[dt][kt] = *(const short8*)(wb + (((dt * 4 + kt) * 64 + lane) << 3));
    }

    for (int t = w_in_m; t < 3125; t += 128) {
        const int node0 = t << 4;
        // A-fragment addressing: row = lane&15 (node within tile),
        // k = q*8 + j within each 32-wide k-tile.
        const float* xr = x + (((size_t)(node0 + ln15) * 16 + m) << 7) + q * 8;

        floatx4 f[8];
        #pragma unroll
        for (int kt = 0; kt < 4; ++kt) {
            f[2 * kt]     = *(const floatx4*)(xr + kt * 32);
            f[2 * kt + 1] = *(const floatx4*)(xr + kt * 32 + 4);
        }

        short8 A[4];
        #pragma unroll
        for (int kt = 0; kt < 4; ++kt) {
            short8 a;
            #pragma unroll
            for (int e = 0; e < 4; ++e) a[e]     = (short)f2bf(f[2 * kt][e]);
            #pragma unroll
            for (int e = 0; e < 4; ++e) a[e + 4] = (short)f2bf(f[2 * kt + 1][e]);
            A[kt] = a;
        }

        floatx4 acc[8];
        #pragma unroll
        for (int dt = 0; dt < 8; ++dt) acc[dt] = (floatx4){0.f, 0.f, 0.f, 0.f};

        #pragma unroll
        for (int kt = 0; kt < 4; ++kt)
            #pragma unroll
            for (int dt = 0; dt < 8; ++dt)
                acc[dt] = __builtin_amdgcn_mfma_f32_16x16x32_bf16(
                    A[kt], B[dt][kt], acc[dt], 0, 0, 0);

        // C/D layout (verified, m89/m91): col = lane&15, row = q*4 + reg.
        float* ob = out + (((size_t)node0 * 16 + m) << 7) + ln15;
        #pragma unroll
        for (int i = 0; i < 4; ++i) {
            float* orow = ob + (size_t)(q * 4 + i) * 2048;  // node stride 16*128
            #pragma unroll
            for (int dt = 0; dt < 8; ++dt) orow[dt * 16] = acc[dt][i];
        }
    }
}

extern "C" void kernel_launch(void* const* d_in, const int* in_sizes, int n_in,
                              void* d_out, int out_size, void* d_ws, size_t ws_size,
                              hipStream_t stream) {
    const float* x   = (const float*)d_in[0];
    const float* w   = (const float*)d_in[1];
    const int*   seg = (const int*)d_in[2];
    float* out = (float*)d_out;
    unsigned short* wp = (unsigned short*)d_ws;  // 65536 ushort = 128 KB

    hipLaunchKernelGGL(pack_weights_kernel, dim3(256), dim3(256), 0, stream, w, wp);
    hipLaunchKernelGGL(irreps_main_kernel, dim3(512), dim3(256), 0, stream,
                       x, wp, seg, out);
}